// Round 6
// baseline (92.371 us; speedup 1.0000x reference)
//
#include <hip/hip_runtime.h>
#include <math.h>

#define N_SAMPLES 524288
#define A_ACT 8
#define D_DIM 64
#define E_DIM 32
#define LOG2PI_F 1.8378770664093453f

#define SORT_THREADS 256
#define CHUNK 4096
#define NBLK (N_SAMPLES / CHUNK)      // 128
#define HIST_SIZE (A_ACT * NBLK)      // 1024
#define SCAN_PER (HIST_SIZE / 256)    // 4

typedef __attribute__((ext_vector_type(8))) short bf16x8;
typedef __attribute__((ext_vector_type(4))) float f32x4;

__device__ __forceinline__ short f2bf(float f) {
  unsigned u = __float_as_uint(f);
  unsigned r = (u + 0x7FFFu + ((u >> 16) & 1u)) >> 16;
  return (short)r;
}

// ---------------- Kernel 1: per-block histogram ----------------
__global__ __launch_bounds__(SORT_THREADS) void hist_kernel(
    const int* __restrict__ idx, int* __restrict__ hist) {
  __shared__ int cnt[A_ACT];
  int t = threadIdx.x;
  if (t < A_ACT) cnt[t] = 0;
  __syncthreads();
  int base = blockIdx.x * CHUNK;
  for (int j = t; j < CHUNK; j += SORT_THREADS) {
    atomicAdd(&cnt[idx[base + j]], 1);
  }
  __syncthreads();
  if (t < A_ACT) hist[t * NBLK + blockIdx.x] = cnt[t];
}

// ---------------- Kernel 2: exclusive scan of hist (1 block) ----------------
__global__ __launch_bounds__(256) void scan_kernel(int* __restrict__ hist) {
  __shared__ int sums[256];
  int t = threadIdx.x;
  int vals[SCAN_PER];
  int s = 0;
#pragma unroll
  for (int k = 0; k < SCAN_PER; ++k) {
    vals[k] = hist[t * SCAN_PER + k];
    s += vals[k];
  }
  sums[t] = s;
  __syncthreads();
  for (int off = 1; off < 256; off <<= 1) {
    int v = (t >= off) ? sums[t - off] : 0;
    __syncthreads();
    sums[t] += v;
    __syncthreads();
  }
  int prefix = (t == 0) ? 0 : sums[t - 1];
#pragma unroll
  for (int k = 0; k < SCAN_PER; ++k) {
    int v = vals[k];
    hist[t * SCAN_PER + k] = prefix;
    prefix += v;
  }
}

// ---------------- Kernel 3: stable scatter (builds p and inv) ----------------
__global__ __launch_bounds__(SORT_THREADS) void scatter_kernel(
    const int* __restrict__ idx, const int* __restrict__ offs,
    int* __restrict__ p, int* __restrict__ inv) {
  __shared__ int base[A_ACT];
  __shared__ int wcnt[4][A_ACT];
  int t = threadIdx.x;
  int wave = t >> 6;
  int lane = t & 63;
  if (t < A_ACT) base[t] = offs[t * NBLK + blockIdx.x];
  __syncthreads();
  int cstart = blockIdx.x * CHUNK;
  for (int pass = 0; pass < CHUNK / SORT_THREADS; ++pass) {
    int i = cstart + pass * SORT_THREADS + t;
    int a = idx[i];
    unsigned long long mymask = 0ULL;
#pragma unroll
    for (int aa = 0; aa < A_ACT; ++aa) {
      unsigned long long m = __ballot(a == aa);
      if (aa == a) mymask = m;
      if (lane == 0) wcnt[wave][aa] = __popcll(m);
    }
    unsigned long long below = (1ULL << lane) - 1ULL;
    int inwave = __popcll(mymask & below);
    __syncthreads();
    int wprefix = 0;
#pragma unroll
    for (int w = 0; w < 4; ++w)
      if (w < wave) wprefix += wcnt[w][a];
    int r = base[a] + wprefix + inwave;
    p[r] = i;
    inv[i] = r;
    __syncthreads();
    if (t < A_ACT) {
      int tot = 0;
#pragma unroll
      for (int w = 0; w < 4; ++w) tot += wcnt[w][t];
      base[t] += tot;
    }
    __syncthreads();
  }
}

// ---------------- Kernel 4: MFMA matvec + rsample + logprob ----------------
// One actor per block; 256 sorted rows. A=[256x64] state (bf16, LDS swizzled),
// B=[64x32] W[a] (bf16, LDS [col][k] swizzled). 4 waves, each 64 rows:
// 4 row-tiles x 2 col-tiles x 2 k-steps of mfma_f32_16x16x32_bf16.
// lp is matmul-independent (exact fp32). LDS 36.25 KB -> 4 blocks/CU.
#define TILE_ROWS 256
#define MAIN_THREADS 256
#define MAIN_BLOCKS (N_SAMPLES / TILE_ROWS + A_ACT)

__global__ __launch_bounds__(MAIN_THREADS, 4) void main_kernel(
    const float* __restrict__ state, const float* __restrict__ W,
    const float* __restrict__ bias, const float* __restrict__ lstd,
    const float* __restrict__ eps, const int* __restrict__ p,
    const int* __restrict__ inv, const int* __restrict__ offs,
    float* __restrict__ out_action, float* __restrict__ out_lp) {
  __shared__ short sA[TILE_ROWS * D_DIM];   // 32 KB bf16, chunk-swizzled
  __shared__ short sB[E_DIM * D_DIM];       // 4 KB bf16 [col][k], swizzled

  int t = threadIdx.x;
  int bid = blockIdx.x;

  // Map block -> (actor, row chunk): each block serves exactly one actor.
  int a = -1, kbase = 0, kend = 0;
  int acc_b = 0;
#pragma unroll
  for (int aa = 0; aa < A_ACT; ++aa) {
    int start = offs[aa * NBLK];
    int end = (aa == A_ACT - 1) ? N_SAMPLES : offs[(aa + 1) * NBLK];
    int cnt = end - start;
    int nc = (cnt + TILE_ROWS - 1) / TILE_ROWS;
    if (a < 0 && bid < acc_b + nc) {
      a = aa;
      int chunk = bid - acc_b;
      kbase = start + chunk * TILE_ROWS;
      kend = min(end, kbase + TILE_ROWS);
    }
    acc_b += nc;
  }
  if (a < 0) return;  // uniform across block
  int nrows = kend - kbase;

  // Stage B: W[a] fp32 [d=k][e=col] -> sB bf16 [col][k], 16B-chunk swizzle.
  {
    int col = t >> 3;          // 0..31
    int kc = t & 7;            // k-chunk 0..7 (8 k's each)
    const float* wp = W + (size_t)a * (D_DIM * E_DIM) + (kc * 8) * E_DIM + col;
    bf16x8 v;
#pragma unroll
    for (int j = 0; j < 8; ++j) v[j] = f2bf(wp[j * E_DIM]);
    *(bf16x8*)(&sB[col * D_DIM + ((kc ^ (col & 7)) << 3)]) = v;
  }

  // Stage A: 16 lanes per row (256B coalesced fp32 read) -> bf16, swizzled.
  {
    int u = t >> 4;            // row-slot 0..15
    int x = t & 15;            // fp32 float4 chunk 0..15
#pragma unroll
    for (int it = 0; it < TILE_ROWS / 16; ++it) {
      int row = it * 16 + u;
      int kc = kbase + min(row, nrows - 1);
      int m = p[kc];
      float4 v = *(const float4*)(state + (size_t)m * D_DIM + x * 4);
      unsigned lo = ((unsigned)(unsigned short)f2bf(v.y) << 16) |
                    (unsigned)(unsigned short)f2bf(v.x);
      unsigned hi = ((unsigned)(unsigned short)f2bf(v.w) << 16) |
                    (unsigned)(unsigned short)f2bf(v.z);
      // bf16 16B-chunk index = x>>1; half = x&1
      int soff = row * D_DIM + (((x >> 1) ^ (row & 7)) << 3) + ((x & 1) << 2);
      *(uint2*)(&sA[soff]) = make_uint2(lo, hi);
    }
  }
  __syncthreads();

  int w = t >> 6;
  int l = t & 63;
  int lrow = l & 15;   // A-row / B-col within tile
  int lk = l >> 4;     // k lane-group 0..3

  f32x4 acc[4][2];
#pragma unroll
  for (int rt = 0; rt < 4; ++rt)
#pragma unroll
    for (int ct = 0; ct < 2; ++ct) acc[rt][ct] = (f32x4){0.f, 0.f, 0.f, 0.f};

#pragma unroll
  for (int ks = 0; ks < 2; ++ks) {
    int kc = ks * 4 + lk;
    bf16x8 aF[4], bF[2];
#pragma unroll
    for (int rt = 0; rt < 4; ++rt) {
      int row = w * 64 + rt * 16 + lrow;
      aF[rt] = *(const bf16x8*)(&sA[row * D_DIM + ((kc ^ (row & 7)) << 3)]);
    }
#pragma unroll
    for (int ct = 0; ct < 2; ++ct) {
      int col = ct * 16 + lrow;
      bF[ct] = *(const bf16x8*)(&sB[col * D_DIM + ((kc ^ (col & 7)) << 3)]);
    }
#pragma unroll
    for (int rt = 0; rt < 4; ++rt)
#pragma unroll
      for (int ct = 0; ct < 2; ++ct)
        acc[rt][ct] = __builtin_amdgcn_mfma_f32_16x16x32_bf16(
            aF[rt], bF[ct], acc[rt][ct], 0, 0, 0);
  }

  // Epilogue. C/D layout: col = lane&15, row = (lane>>4)*4 + reg (m89).
  float bc[2], lsc[2], sdc[2];
#pragma unroll
  for (int ct = 0; ct < 2; ++ct) {
    int col = ct * 16 + lrow;
    bc[ct] = bias[a * E_DIM + col];
    lsc[ct] = lstd[a * E_DIM + col];
    sdc[ct] = expf(lsc[ct]);
  }

#pragma unroll
  for (int rt = 0; rt < 4; ++rt) {
    int rbase = w * 64 + rt * 16 + lk * 4;
#pragma unroll
    for (int r = 0; r < 4; ++r) {
      int rl = rbase + r;
      bool valid = (rl < nrows);
      int krc = kbase + (valid ? rl : (nrows - 1));
      int dest = inv[krc];
      float lpp = 0.f;
#pragma unroll
      for (int ct = 0; ct < 2; ++ct) {
        float ev = eps[(size_t)krc * E_DIM + ct * 16 + lrow];
        float action = fmaf(sdc[ct], ev, acc[rt][ct][r] + bc[ct]);
        lpp = fmaf(-0.5f * ev, ev, lpp) - lsc[ct];
        if (valid)
          out_action[(size_t)dest * E_DIM + ct * 16 + lrow] = action;
      }
      lpp += __shfl_xor(lpp, 1, 64);
      lpp += __shfl_xor(lpp, 2, 64);
      lpp += __shfl_xor(lpp, 4, 64);
      lpp += __shfl_xor(lpp, 8, 64);
      if (valid && lrow == 0) out_lp[dest] = lpp - 16.0f * LOG2PI_F;
    }
  }
}

extern "C" void kernel_launch(void* const* d_in, const int* in_sizes, int n_in,
                              void* d_out, int out_size, void* d_ws, size_t ws_size,
                              hipStream_t stream) {
  const float* state = (const float*)d_in[0];
  const float* W     = (const float*)d_in[1];
  const float* b     = (const float*)d_in[2];
  const float* ls    = (const float*)d_in[3];
  const float* eps   = (const float*)d_in[4];
  const int*   idx   = (const int*)d_in[5];

  float* out_action = (float*)d_out;                              // [N, E]
  float* out_lp     = (float*)d_out + (size_t)N_SAMPLES * E_DIM;  // [N]

  int* p    = (int*)d_ws;
  int* inv  = p + N_SAMPLES;
  int* hist = inv + N_SAMPLES;

  hipLaunchKernelGGL(hist_kernel, dim3(NBLK), dim3(SORT_THREADS), 0, stream,
                     idx, hist);
  hipLaunchKernelGGL(scan_kernel, dim3(1), dim3(256), 0, stream, hist);
  hipLaunchKernelGGL(scatter_kernel, dim3(NBLK), dim3(SORT_THREADS), 0, stream,
                     idx, hist, p, inv);
  hipLaunchKernelGGL(main_kernel, dim3(MAIN_BLOCKS), dim3(MAIN_THREADS),
                     0, stream, state, W, b, ls, eps, p, inv, hist,
                     out_action, out_lp);
}

// Round 8
// 66.109 us; speedup vs baseline: 1.3973x; 1.3973x over previous
//
#include <hip/hip_runtime.h>
#include <math.h>

#define N_SAMPLES 524288
#define A_ACT 8
#define D_DIM 64
#define E_DIM 32
#define LOG2PI_F 1.8378770664093453f

#define SORT_THREADS 256
#define CHUNK 1024
#define NBLK (N_SAMPLES / CHUNK)      // 512
#define HIST_SIZE (A_ACT * NBLK)      // 4096
#define SCAN_PER (HIST_SIZE / 256)    // 16

typedef __attribute__((ext_vector_type(8))) short bf16x8;
typedef __attribute__((ext_vector_type(4))) float f32x4;

__device__ __forceinline__ short f2bf(float f) {
  unsigned u = __float_as_uint(f);
  unsigned r = (u + 0x7FFFu + ((u >> 16) & 1u)) >> 16;
  return (short)r;
}

// ---------------- Kernel 1: per-chunk histogram ----------------
__global__ __launch_bounds__(SORT_THREADS) void hist_kernel(
    const int* __restrict__ idx, int* __restrict__ hist) {
  __shared__ int cnt[A_ACT];
  int t = threadIdx.x;
  if (t < A_ACT) cnt[t] = 0;
  __syncthreads();
  int base = blockIdx.x * CHUNK;
#pragma unroll
  for (int j = 0; j < CHUNK / SORT_THREADS; ++j) {
    atomicAdd(&cnt[idx[base + j * SORT_THREADS + t]], 1);
  }
  __syncthreads();
  if (t < A_ACT) hist[t * NBLK + blockIdx.x] = cnt[t];
}

// ---------------- Kernel 2: exclusive scan of hist (1 block) ----------------
__global__ __launch_bounds__(256) void scan_kernel(int* __restrict__ hist) {
  __shared__ int sums[256];
  int t = threadIdx.x;
  int vals[SCAN_PER];
  int s = 0;
#pragma unroll
  for (int k = 0; k < SCAN_PER; ++k) {
    vals[k] = hist[t * SCAN_PER + k];
    s += vals[k];
  }
  sums[t] = s;
  __syncthreads();
  for (int off = 1; off < 256; off <<= 1) {
    int v = (t >= off) ? sums[t - off] : 0;
    __syncthreads();
    sums[t] += v;
    __syncthreads();
  }
  int prefix = (t == 0) ? 0 : sums[t - 1];
#pragma unroll
  for (int k = 0; k < SCAN_PER; ++k) {
    int v = vals[k];
    hist[t * SCAN_PER + k] = prefix;
    prefix += v;
  }
}

// ---------------- Kernel 3: stable scatter (builds p and inv) ----------------
__global__ __launch_bounds__(SORT_THREADS) void scatter_kernel(
    const int* __restrict__ idx, const int* __restrict__ offs,
    int* __restrict__ p, int* __restrict__ inv) {
  __shared__ int base[A_ACT];
  __shared__ int wcnt[4][A_ACT];
  int t = threadIdx.x;
  int wave = t >> 6;
  int lane = t & 63;
  if (t < A_ACT) base[t] = offs[t * NBLK + blockIdx.x];
  __syncthreads();
  int cstart = blockIdx.x * CHUNK;
#pragma unroll
  for (int pass = 0; pass < CHUNK / SORT_THREADS; ++pass) {   // 4 passes
    int i = cstart + pass * SORT_THREADS + t;
    int a = idx[i];
    unsigned long long mymask = 0ULL;
#pragma unroll
    for (int aa = 0; aa < A_ACT; ++aa) {
      unsigned long long m = __ballot(a == aa);
      if (aa == a) mymask = m;
      if (lane == 0) wcnt[wave][aa] = __popcll(m);
    }
    unsigned long long below = (1ULL << lane) - 1ULL;
    int inwave = __popcll(mymask & below);
    __syncthreads();
    int wprefix = 0;
#pragma unroll
    for (int w = 0; w < 4; ++w)
      if (w < wave) wprefix += wcnt[w][a];
    int r = base[a] + wprefix + inwave;
    p[r] = i;
    inv[i] = r;
    __syncthreads();
    if (t < A_ACT) {
      int tot = 0;
#pragma unroll
      for (int w = 0; w < 4; ++w) tot += wcnt[w][t];
      base[t] += tot;
    }
    __syncthreads();
  }
}

// ---------------- Kernel 4: MFMA matvec + rsample + logprob ----------------
// One actor per block; 256 sorted rows. A=[256x64] state bf16 (LDS swizzled),
// B=[64x32] W[a] bf16 (LDS [col][k] swizzled). 4 waves x 16 MFMA.
// After MFMA, acc -> LDS (aliasing sA, swizzled), then vectorized epilogue:
// coalesced float4 eps, float4 out stores (8 lanes/row), shfl lp reduce.
#define TILE_ROWS 256
#define MAIN_THREADS 256
#define MAIN_BLOCKS (N_SAMPLES / TILE_ROWS + A_ACT)

__global__ __launch_bounds__(MAIN_THREADS, 4) void main_kernel(
    const float* __restrict__ state, const float* __restrict__ W,
    const float* __restrict__ bias, const float* __restrict__ lstd,
    const float* __restrict__ eps, const int* __restrict__ p,
    const int* __restrict__ inv, const int* __restrict__ offs,
    float* __restrict__ out_action, float* __restrict__ out_lp) {
  __shared__ short sA[TILE_ROWS * D_DIM];   // 32 KB bf16; aliased as sC fp32
  __shared__ short sB[E_DIM * D_DIM];       // 4 KB bf16 [col][k], swizzled
  __shared__ int s_d[TILE_ROWS];            // dest rows

  int t = threadIdx.x;
  int bid = blockIdx.x;

  // Map block -> (actor, row chunk): each block serves exactly one actor.
  int a = -1, kbase = 0, kend = 0;
  int acc_b = 0;
#pragma unroll
  for (int aa = 0; aa < A_ACT; ++aa) {
    int start = offs[aa * NBLK];
    int end = (aa == A_ACT - 1) ? N_SAMPLES : offs[(aa + 1) * NBLK];
    int cnt = end - start;
    int nc = (cnt + TILE_ROWS - 1) / TILE_ROWS;
    if (a < 0 && bid < acc_b + nc) {
      a = aa;
      int chunk = bid - acc_b;
      kbase = start + chunk * TILE_ROWS;
      kend = min(end, kbase + TILE_ROWS);
    }
    acc_b += nc;
  }
  if (a < 0) return;  // uniform across block
  int nrows = kend - kbase;

  // dest rows (clamped)
  s_d[t] = inv[kbase + min(t, nrows - 1)];

  // Stage B: W[a] fp32 [d=k][e=col] -> sB bf16 [col][k], 16B-chunk swizzle.
  {
    int col = t >> 3;          // 0..31
    int kc = t & 7;            // k-chunk 0..7 (8 k's each)
    const float* wp = W + (size_t)a * (D_DIM * E_DIM) + (kc * 8) * E_DIM + col;
    bf16x8 v;
#pragma unroll
    for (int j = 0; j < 8; ++j) v[j] = f2bf(wp[j * E_DIM]);
    *(bf16x8*)(&sB[col * D_DIM + ((kc ^ (col & 7)) << 3)]) = v;
  }

  // Stage A: 16 lanes per row (256B coalesced fp32 read) -> bf16, swizzled.
  {
    int u = t >> 4;            // row-slot 0..15
    int x = t & 15;            // fp32 float4 chunk 0..15
#pragma unroll
    for (int it = 0; it < TILE_ROWS / 16; ++it) {
      int row = it * 16 + u;
      int kc = kbase + min(row, nrows - 1);
      int m = p[kc];
      float4 v = *(const float4*)(state + (size_t)m * D_DIM + x * 4);
      unsigned lo = ((unsigned)(unsigned short)f2bf(v.y) << 16) |
                    (unsigned)(unsigned short)f2bf(v.x);
      unsigned hi = ((unsigned)(unsigned short)f2bf(v.w) << 16) |
                    (unsigned)(unsigned short)f2bf(v.z);
      int soff = row * D_DIM + (((x >> 1) ^ (row & 7)) << 3) + ((x & 1) << 2);
      *(uint2*)(&sA[soff]) = make_uint2(lo, hi);
    }
  }
  __syncthreads();

  int w = t >> 6;
  int l = t & 63;
  int lrow = l & 15;   // A-row / B-col within tile
  int lk = l >> 4;     // k lane-group 0..3

  f32x4 acc[4][2];
#pragma unroll
  for (int rt = 0; rt < 4; ++rt)
#pragma unroll
    for (int ct = 0; ct < 2; ++ct) acc[rt][ct] = (f32x4){0.f, 0.f, 0.f, 0.f};

#pragma unroll
  for (int ks = 0; ks < 2; ++ks) {
    int kc = ks * 4 + lk;
    bf16x8 aF[4], bF[2];
#pragma unroll
    for (int rt = 0; rt < 4; ++rt) {
      int row = w * 64 + rt * 16 + lrow;
      aF[rt] = *(const bf16x8*)(&sA[row * D_DIM + ((kc ^ (row & 7)) << 3)]);
    }
#pragma unroll
    for (int ct = 0; ct < 2; ++ct) {
      int col = ct * 16 + lrow;
      bF[ct] = *(const bf16x8*)(&sB[col * D_DIM + ((kc ^ (col & 7)) << 3)]);
    }
#pragma unroll
    for (int rt = 0; rt < 4; ++rt)
#pragma unroll
      for (int ct = 0; ct < 2; ++ct)
        acc[rt][ct] = __builtin_amdgcn_mfma_f32_16x16x32_bf16(
            aF[rt], bF[ct], acc[rt][ct], 0, 0, 0);
  }

  __syncthreads();   // all sA reads done; safe to alias as sC

  // Dump acc to LDS. C/D layout: col = lane&15, row = (lane>>4)*4 + reg.
  // Swizzle 16B chunks of each row by (row&7) -> 2-way banks (free).
  float* sC = (float*)sA;   // [256 rows][32 cols], chunk-swizzled
#pragma unroll
  for (int rt = 0; rt < 4; ++rt) {
#pragma unroll
    for (int ct = 0; ct < 2; ++ct) {
      int col = ct * 16 + lrow;
#pragma unroll
      for (int r = 0; r < 4; ++r) {
        int row = w * 64 + rt * 16 + lk * 4 + r;
        sC[row * E_DIM + (((col >> 2) ^ (row & 7)) << 2) + (col & 3)] =
            acc[rt][ct][r];
      }
    }
  }
  __syncthreads();

  // Vectorized epilogue: 8 lanes per row, float4 everywhere.
  int c = t & 7;            // col chunk 0..7 (4 cols)
  float4 bv = *(const float4*)(bias + a * E_DIM + c * 4);
  float4 lv = *(const float4*)(lstd + a * E_DIM + c * 4);
  const float bva[4] = {bv.x, bv.y, bv.z, bv.w};
  const float lsa[4] = {lv.x, lv.y, lv.z, lv.w};
  float sda[4];
#pragma unroll
  for (int j = 0; j < 4; ++j) sda[j] = expf(lsa[j]);
  float lsum = lsa[0] + lsa[1] + lsa[2] + lsa[3];

#pragma unroll
  for (int pass = 0; pass < 8; ++pass) {
    int row = pass * 32 + (t >> 3);
    bool valid = (row < nrows);
    int krc = kbase + (valid ? row : (nrows - 1));
    int dest = s_d[valid ? row : (nrows - 1)];
    float4 ev = *(const float4*)(eps + (size_t)krc * E_DIM + c * 4);
    float4 av = *(const float4*)(&sC[row * E_DIM + ((c ^ (row & 7)) << 2)]);
    const float ep[4] = {ev.x, ev.y, ev.z, ev.w};
    const float ac[4] = {av.x, av.y, av.z, av.w};
    float o[4];
    float part = -lsum;
#pragma unroll
    for (int j = 0; j < 4; ++j) {
      o[j] = fmaf(sda[j], ep[j], ac[j] + bva[j]);
      part = fmaf(-0.5f * ep[j], ep[j], part);
    }
    part += __shfl_xor(part, 1, 64);
    part += __shfl_xor(part, 2, 64);
    part += __shfl_xor(part, 4, 64);
    if (valid) {
      *(float4*)(&out_action[(size_t)dest * E_DIM + c * 4]) =
          make_float4(o[0], o[1], o[2], o[3]);
      if (c == 0) out_lp[dest] = part - 16.0f * LOG2PI_F;
    }
  }
}

extern "C" void kernel_launch(void* const* d_in, const int* in_sizes, int n_in,
                              void* d_out, int out_size, void* d_ws, size_t ws_size,
                              hipStream_t stream) {
  const float* state = (const float*)d_in[0];
  const float* W     = (const float*)d_in[1];
  const float* b     = (const float*)d_in[2];
  const float* ls    = (const float*)d_in[3];
  const float* eps   = (const float*)d_in[4];
  const int*   idx   = (const int*)d_in[5];

  float* out_action = (float*)d_out;                              // [N, E]
  float* out_lp     = (float*)d_out + (size_t)N_SAMPLES * E_DIM;  // [N]

  int* p    = (int*)d_ws;
  int* inv  = p + N_SAMPLES;
  int* hist = inv + N_SAMPLES;

  hipLaunchKernelGGL(hist_kernel, dim3(NBLK), dim3(SORT_THREADS), 0, stream,
                     idx, hist);
  hipLaunchKernelGGL(scan_kernel, dim3(1), dim3(256), 0, stream, hist);
  hipLaunchKernelGGL(scatter_kernel, dim3(NBLK), dim3(SORT_THREADS), 0, stream,
                     idx, hist, p, inv);
  hipLaunchKernelGGL(main_kernel, dim3(MAIN_BLOCKS), dim3(MAIN_THREADS),
                     0, stream, state, W, b, ls, eps, p, inv, hist,
                     out_action, out_lp);
}

// Round 9
// 63.378 us; speedup vs baseline: 1.4575x; 1.0431x over previous
//
#include <hip/hip_runtime.h>
#include <math.h>

#define N_SAMPLES 524288
#define A_ACT 8
#define D_DIM 64
#define E_DIM 32
#define LOG2PI_F 1.8378770664093453f

#define SORT_THREADS 256
#define CHUNK 1024
#define NBLK (N_SAMPLES / CHUNK)      // 512
#define HIST_SIZE (A_ACT * NBLK)      // 4096
#define SCAN_PER (HIST_SIZE / 256)    // 16

typedef __attribute__((ext_vector_type(8))) short bf16x8;
typedef __attribute__((ext_vector_type(4))) float f32x4;

__device__ __forceinline__ short f2bf(float f) {
  unsigned u = __float_as_uint(f);
  unsigned r = (u + 0x7FFFu + ((u >> 16) & 1u)) >> 16;
  return (short)r;
}

// ---------------- Kernel 1: per-chunk histogram ----------------
__global__ __launch_bounds__(SORT_THREADS) void hist_kernel(
    const int* __restrict__ idx, int* __restrict__ hist) {
  __shared__ int cnt[A_ACT];
  int t = threadIdx.x;
  if (t < A_ACT) cnt[t] = 0;
  __syncthreads();
  int base = blockIdx.x * CHUNK;
#pragma unroll
  for (int j = 0; j < CHUNK / SORT_THREADS; ++j) {
    atomicAdd(&cnt[idx[base + j * SORT_THREADS + t]], 1);
  }
  __syncthreads();
  if (t < A_ACT) hist[t * NBLK + blockIdx.x] = cnt[t];
}

// ---------------- Kernel 2: exclusive scan of hist (1 block) ----------------
__global__ __launch_bounds__(256) void scan_kernel(int* __restrict__ hist) {
  __shared__ int sums[256];
  int t = threadIdx.x;
  int vals[SCAN_PER];
  int s = 0;
#pragma unroll
  for (int k = 0; k < SCAN_PER; ++k) {
    vals[k] = hist[t * SCAN_PER + k];
    s += vals[k];
  }
  sums[t] = s;
  __syncthreads();
  for (int off = 1; off < 256; off <<= 1) {
    int v = (t >= off) ? sums[t - off] : 0;
    __syncthreads();
    sums[t] += v;
    __syncthreads();
  }
  int prefix = (t == 0) ? 0 : sums[t - 1];
#pragma unroll
  for (int k = 0; k < SCAN_PER; ++k) {
    int v = vals[k];
    hist[t * SCAN_PER + k] = prefix;
    prefix += v;
  }
}

// ---------------- Kernel 3: stable scatter (builds p and inv) ----------------
__global__ __launch_bounds__(SORT_THREADS) void scatter_kernel(
    const int* __restrict__ idx, const int* __restrict__ offs,
    int* __restrict__ p, int* __restrict__ inv) {
  __shared__ int base[A_ACT];
  __shared__ int wcnt[4][A_ACT];
  int t = threadIdx.x;
  int wave = t >> 6;
  int lane = t & 63;
  if (t < A_ACT) base[t] = offs[t * NBLK + blockIdx.x];
  __syncthreads();
  int cstart = blockIdx.x * CHUNK;
#pragma unroll
  for (int pass = 0; pass < CHUNK / SORT_THREADS; ++pass) {   // 4 passes
    int i = cstart + pass * SORT_THREADS + t;
    int a = idx[i];
    unsigned long long mymask = 0ULL;
#pragma unroll
    for (int aa = 0; aa < A_ACT; ++aa) {
      unsigned long long m = __ballot(a == aa);
      if (aa == a) mymask = m;
      if (lane == 0) wcnt[wave][aa] = __popcll(m);
    }
    unsigned long long below = (1ULL << lane) - 1ULL;
    int inwave = __popcll(mymask & below);
    __syncthreads();
    int wprefix = 0;
#pragma unroll
    for (int w = 0; w < 4; ++w)
      if (w < wave) wprefix += wcnt[w][a];
    int r = base[a] + wprefix + inwave;
    p[r] = i;
    inv[i] = r;
    __syncthreads();
    if (t < A_ACT) {
      int tot = 0;
#pragma unroll
      for (int w = 0; w < 4; ++w) tot += wcnt[w][t];
      base[t] += tot;
    }
    __syncthreads();
  }
}

// ---------------- Kernel 4: MFMA matvec + rsample + logprob ----------------
// One actor per block; 128 sorted rows (small tile -> 7 blocks/CU for
// latency overlap on the random state-row gather). 4 waves x 8 MFMA.
// acc -> LDS (aliasing sA, swizzled) -> vectorized coalesced epilogue.
#define TILE_ROWS 128
#define MAIN_THREADS 256
#define MAIN_BLOCKS (N_SAMPLES / TILE_ROWS + A_ACT)

__global__ __launch_bounds__(MAIN_THREADS, 6) void main_kernel(
    const float* __restrict__ state, const float* __restrict__ W,
    const float* __restrict__ bias, const float* __restrict__ lstd,
    const float* __restrict__ eps, const int* __restrict__ p,
    const int* __restrict__ inv, const int* __restrict__ offs,
    float* __restrict__ out_action, float* __restrict__ out_lp) {
  __shared__ short sA[TILE_ROWS * D_DIM];   // 16 KB bf16; aliased as sC fp32
  __shared__ short sB[E_DIM * D_DIM];       // 4 KB bf16 [col][k], swizzled
  __shared__ int s_d[TILE_ROWS];            // dest rows

  int t = threadIdx.x;
  int bid = blockIdx.x;

  // Map block -> (actor, row chunk): each block serves exactly one actor.
  int a = -1, kbase = 0, kend = 0;
  int acc_b = 0;
#pragma unroll
  for (int aa = 0; aa < A_ACT; ++aa) {
    int start = offs[aa * NBLK];
    int end = (aa == A_ACT - 1) ? N_SAMPLES : offs[(aa + 1) * NBLK];
    int cnt = end - start;
    int nc = (cnt + TILE_ROWS - 1) / TILE_ROWS;
    if (a < 0 && bid < acc_b + nc) {
      a = aa;
      int chunk = bid - acc_b;
      kbase = start + chunk * TILE_ROWS;
      kend = min(end, kbase + TILE_ROWS);
    }
    acc_b += nc;
  }
  if (a < 0) return;  // uniform across block
  int nrows = kend - kbase;

  // dest rows (clamped, coalesced)
  if (t < TILE_ROWS) s_d[t] = inv[kbase + min(t, nrows - 1)];

  // Stage B: W[a] fp32 [d=k][e=col] -> sB bf16 [col][k], 16B-chunk swizzle.
  {
    int col = t >> 3;          // 0..31
    int kc = t & 7;            // k-chunk 0..7 (8 k's each)
    const float* wp = W + (size_t)a * (D_DIM * E_DIM) + (kc * 8) * E_DIM + col;
    bf16x8 v;
#pragma unroll
    for (int j = 0; j < 8; ++j) v[j] = f2bf(wp[j * E_DIM]);
    *(bf16x8*)(&sB[col * D_DIM + ((kc ^ (col & 7)) << 3)]) = v;
  }

  // Stage A: 16 lanes per row (256B coalesced fp32 read) -> bf16, swizzled.
  // Prefetch the p[] indices first (independent), then gather state.
  {
    int u = t >> 4;            // row-slot 0..15
    int x = t & 15;            // fp32 float4 chunk 0..15
    int pm[TILE_ROWS / 16];
#pragma unroll
    for (int it = 0; it < TILE_ROWS / 16; ++it) {   // 8 iters
      int row = it * 16 + u;
      pm[it] = p[kbase + min(row, nrows - 1)];
    }
#pragma unroll
    for (int it = 0; it < TILE_ROWS / 16; ++it) {
      int row = it * 16 + u;
      float4 v = *(const float4*)(state + (size_t)pm[it] * D_DIM + x * 4);
      unsigned lo = ((unsigned)(unsigned short)f2bf(v.y) << 16) |
                    (unsigned)(unsigned short)f2bf(v.x);
      unsigned hi = ((unsigned)(unsigned short)f2bf(v.w) << 16) |
                    (unsigned)(unsigned short)f2bf(v.z);
      int soff = row * D_DIM + (((x >> 1) ^ (row & 7)) << 3) + ((x & 1) << 2);
      *(uint2*)(&sA[soff]) = make_uint2(lo, hi);
    }
  }
  __syncthreads();

  int w = t >> 6;
  int l = t & 63;
  int lrow = l & 15;   // A-row / B-col within tile
  int lk = l >> 4;     // k lane-group 0..3

  f32x4 acc[2][2];
#pragma unroll
  for (int rt = 0; rt < 2; ++rt)
#pragma unroll
    for (int ct = 0; ct < 2; ++ct) acc[rt][ct] = (f32x4){0.f, 0.f, 0.f, 0.f};

#pragma unroll
  for (int ks = 0; ks < 2; ++ks) {
    int kc = ks * 4 + lk;
    bf16x8 aF[2], bF[2];
#pragma unroll
    for (int rt = 0; rt < 2; ++rt) {
      int row = w * 32 + rt * 16 + lrow;
      aF[rt] = *(const bf16x8*)(&sA[row * D_DIM + ((kc ^ (row & 7)) << 3)]);
    }
#pragma unroll
    for (int ct = 0; ct < 2; ++ct) {
      int col = ct * 16 + lrow;
      bF[ct] = *(const bf16x8*)(&sB[col * D_DIM + ((kc ^ (col & 7)) << 3)]);
    }
#pragma unroll
    for (int rt = 0; rt < 2; ++rt)
#pragma unroll
      for (int ct = 0; ct < 2; ++ct)
        acc[rt][ct] = __builtin_amdgcn_mfma_f32_16x16x32_bf16(
            aF[rt], bF[ct], acc[rt][ct], 0, 0, 0);
  }

  __syncthreads();   // all sA reads done; safe to alias as sC

  // Dump acc to LDS. C/D layout: col = lane&15, row = (lane>>4)*4 + reg.
  float* sC = (float*)sA;   // [128 rows][32 cols], 16B-chunk swizzled
#pragma unroll
  for (int rt = 0; rt < 2; ++rt) {
#pragma unroll
    for (int ct = 0; ct < 2; ++ct) {
      int col = ct * 16 + lrow;
#pragma unroll
      for (int r = 0; r < 4; ++r) {
        int row = w * 32 + rt * 16 + lk * 4 + r;
        sC[row * E_DIM + (((col >> 2) ^ (row & 7)) << 2) + (col & 3)] =
            acc[rt][ct][r];
      }
    }
  }
  __syncthreads();

  // Vectorized epilogue: 8 lanes per row, float4 everywhere.
  int c = t & 7;            // col chunk 0..7 (4 cols)
  float4 bv = *(const float4*)(bias + a * E_DIM + c * 4);
  float4 lv = *(const float4*)(lstd + a * E_DIM + c * 4);
  const float bva[4] = {bv.x, bv.y, bv.z, bv.w};
  const float lsa[4] = {lv.x, lv.y, lv.z, lv.w};
  float sda[4];
#pragma unroll
  for (int j = 0; j < 4; ++j) sda[j] = expf(lsa[j]);
  float lsum = lsa[0] + lsa[1] + lsa[2] + lsa[3];

#pragma unroll
  for (int pass = 0; pass < TILE_ROWS / 32; ++pass) {   // 4 passes
    int row = pass * 32 + (t >> 3);
    bool valid = (row < nrows);
    int rc = valid ? row : (nrows - 1);
    int krc = kbase + rc;
    int dest = s_d[rc];
    float4 ev = *(const float4*)(eps + (size_t)krc * E_DIM + c * 4);
    float4 av = *(const float4*)(&sC[row * E_DIM + ((c ^ (row & 7)) << 2)]);
    const float ep[4] = {ev.x, ev.y, ev.z, ev.w};
    const float ac[4] = {av.x, av.y, av.z, av.w};
    float o[4];
    float part = -lsum;
#pragma unroll
    for (int j = 0; j < 4; ++j) {
      o[j] = fmaf(sda[j], ep[j], ac[j] + bva[j]);
      part = fmaf(-0.5f * ep[j], ep[j], part);
    }
    part += __shfl_xor(part, 1, 64);
    part += __shfl_xor(part, 2, 64);
    part += __shfl_xor(part, 4, 64);
    if (valid) {
      *(float4*)(&out_action[(size_t)dest * E_DIM + c * 4]) =
          make_float4(o[0], o[1], o[2], o[3]);
      if (c == 0) out_lp[dest] = part - 16.0f * LOG2PI_F;
    }
  }
}

extern "C" void kernel_launch(void* const* d_in, const int* in_sizes, int n_in,
                              void* d_out, int out_size, void* d_ws, size_t ws_size,
                              hipStream_t stream) {
  const float* state = (const float*)d_in[0];
  const float* W     = (const float*)d_in[1];
  const float* b     = (const float*)d_in[2];
  const float* ls    = (const float*)d_in[3];
  const float* eps   = (const float*)d_in[4];
  const int*   idx   = (const int*)d_in[5];

  float* out_action = (float*)d_out;                              // [N, E]
  float* out_lp     = (float*)d_out + (size_t)N_SAMPLES * E_DIM;  // [N]

  int* p    = (int*)d_ws;
  int* inv  = p + N_SAMPLES;
  int* hist = inv + N_SAMPLES;

  hipLaunchKernelGGL(hist_kernel, dim3(NBLK), dim3(SORT_THREADS), 0, stream,
                     idx, hist);
  hipLaunchKernelGGL(scan_kernel, dim3(1), dim3(256), 0, stream, hist);
  hipLaunchKernelGGL(scatter_kernel, dim3(NBLK), dim3(SORT_THREADS), 0, stream,
                     idx, hist, p, inv);
  hipLaunchKernelGGL(main_kernel, dim3(MAIN_BLOCKS), dim3(MAIN_THREADS),
                     0, stream, state, W, b, ls, eps, p, inv, hist,
                     out_action, out_lp);
}